// Round 8
// baseline (317.008 us; speedup 1.0000x reference)
//
#include <hip/hip_runtime.h>
#include <hip/hip_bf16.h>

typedef __bf16 bf16;
typedef _Float16 half_t;
typedef bf16 bf16x8 __attribute__((ext_vector_type(8)));
typedef bf16 bf16x4 __attribute__((ext_vector_type(4)));
typedef float floatx4 __attribute__((ext_vector_type(4)));

#define B_ 32
#define N_ 196
#define H_ 8
#define D_ 1024
#define DK_ 128
#define BN_ (B_ * N_)   // 6272
#define BH_ (B_ * H_)   // 256
#define NPAD_ 224       // padded N for S rows / Vt cols
#define PSTRIDE_ 232    // LDS P-tile col stride (16B aligned, bank-spread)

#define KT_ 16          // K tiles (BK=64), 1024 = 16*64 exact

typedef __attribute__((address_space(3))) unsigned int lds_uint;
typedef const __attribute__((address_space(1))) unsigned int glb_uint;

__device__ __forceinline__ void async_copy16(const bf16* g, bf16* l) {
  __builtin_amdgcn_global_load_lds((glb_uint*)g, (lds_uint*)l, 16, 0, 0);
}

#define BARRIER() asm volatile("s_barrier" ::: "memory")
#define WAITV0() asm volatile("s_waitcnt vmcnt(0)" ::: "memory")

// ---------------------------------------------------------------------------
// Batched f32 -> bf16 convert: blockIdx.y selects which tensor (same size).
// ---------------------------------------------------------------------------
__global__ __launch_bounds__(256) void cvt3_kernel(const float* __restrict__ s0,
                                                   const float* __restrict__ s1,
                                                   const float* __restrict__ s2,
                                                   bf16* __restrict__ d0,
                                                   bf16* __restrict__ d1,
                                                   bf16* __restrict__ d2, int n4) {
  const int which = blockIdx.y;
  const float* s = (which == 0) ? s0 : (which == 1) ? s1 : s2;
  bf16* d = (which == 0) ? d0 : (which == 1) ? d1 : d2;
  int i = blockIdx.x * 256 + threadIdx.x;
  if (i >= n4) return;
  float4 v = ((const float4*)s)[i];
  bf16x4 o;
  o[0] = (bf16)v.x;
  o[1] = (bf16)v.y;
  o[2] = (bf16)v.z;
  o[3] = (bf16)v.w;
  *(bf16x4*)(d + (size_t)i * 4) = o;
}

__global__ __launch_bounds__(256) void cvt4_kernel(const float* __restrict__ s0,
                                                   const float* __restrict__ s1,
                                                   const float* __restrict__ s2,
                                                   const float* __restrict__ s3,
                                                   bf16* __restrict__ d0,
                                                   bf16* __restrict__ d1,
                                                   bf16* __restrict__ d2,
                                                   bf16* __restrict__ d3, int n4) {
  const int which = blockIdx.y;
  const float* s = (which == 0) ? s0 : (which == 1) ? s1 : (which == 2) ? s2 : s3;
  bf16* d = (which == 0) ? d0 : (which == 1) ? d1 : (which == 2) ? d2 : d3;
  int i = blockIdx.x * 256 + threadIdx.x;
  if (i >= n4) return;
  float4 v = ((const float4*)s)[i];
  bf16x4 o;
  o[0] = (bf16)v.x;
  o[1] = (bf16)v.y;
  o[2] = (bf16)v.z;
  o[3] = (bf16)v.w;
  *(bf16x4*)(d + (size_t)i * 4) = o;
}

// ---------------------------------------------------------------------------
// Geometry weights (LINEAR domain): S[b,h,n,m] = max(relu(geo . WG_w[h] + b), 1e-6)
// stored f16. softmax(log w + s) == w*exp(s)/sum(w*exp(s)), so attn multiplies.
// ---------------------------------------------------------------------------
__global__ __launch_bounds__(256) void geo_kernel(const float* __restrict__ box,
                                                  const float* __restrict__ WGw,
                                                  const float* __restrict__ WGb,
                                                  half_t* __restrict__ S) {
  __shared__ float4 wsh[128];
  if (threadIdx.x < 128) wsh[threadIdx.x] = ((const float4*)WGw)[threadIdx.x];
  __syncthreads();

  int tid = blockIdx.x * 256 + threadIdx.x;
  int b = tid / (N_ * N_);
  int rem = tid - b * (N_ * N_);
  int n = rem / N_;
  int m = rem - n * N_;

  float4 bn = ((const float4*)box)[b * N_ + n];
  float4 bm = ((const float4*)box)[b * N_ + m];
  float cxn = (bn.x + bn.z) * 0.5f, cyn = (bn.y + bn.w) * 0.5f;
  float wn = bn.z - bn.x + 1.0f, hn = bn.w - bn.y + 1.0f;
  float cxm = (bm.x + bm.z) * 0.5f, cym = (bm.y + bm.w) * 0.5f;
  float wm = bm.z - bm.x + 1.0f, hm = bm.w - bm.y + 1.0f;

  float pos[4];
  pos[0] = __logf(fmaxf(fabsf((cxn - cxm) / wn), 1e-3f));
  pos[1] = __logf(fmaxf(fabsf((cyn - cym) / hn), 1e-3f));
  pos[2] = __logf(wn / wm);
  pos[3] = __logf(hn / hm);

  const float dims[8] = {1.0f,          0.4216965034f, 0.1778279410f, 0.0749894209f,
                         0.0316227766f, 0.0133352143f, 0.0056234133f, 0.0023713737f};
  float feat[64];
#pragma unroll
  for (int p = 0; p < 4; p++) {
#pragma unroll
    for (int f = 0; f < 8; f++) {
      float a = 100.0f * pos[p] * dims[f];
      feat[p * 8 + f] = __sinf(a);
      feat[32 + p * 8 + f] = __cosf(a);
    }
  }
#pragma unroll
  for (int hh = 0; hh < 8; hh++) {
    float accv = WGb[hh];
#pragma unroll
    for (int g4 = 0; g4 < 16; g4++) {
      float4 wv = wsh[hh * 16 + g4];
      accv += feat[g4 * 4 + 0] * wv.x + feat[g4 * 4 + 1] * wv.y +
              feat[g4 * 4 + 2] * wv.z + feat[g4 * 4 + 3] * wv.w;
    }
    S[((size_t)((b * H_ + hh) * N_ + n)) * NPAD_ + m] = (half_t)fmaxf(accv, 1e-6f);
  }
}

// ---------------------------------------------------------------------------
// 2-phase NT GEMM (round-7 structure, UNCHANGED this round): 128x128 tile,
// BK=64, 4 waves, double-buffered LDS, conflict-free XOR swizzle, setprio,
// XCD-chunked block swizzle (FETCH 155->48 MB verified round 7).
// ---------------------------------------------------------------------------
template <int VARIANT>
__global__ __launch_bounds__(256, 2) void gemm2p(
    const bf16* __restrict__ A0, const bf16* __restrict__ A1, const bf16* __restrict__ A2,
    const bf16* __restrict__ W0, const bf16* __restrict__ W1, const bf16* __restrict__ W2,
    const float* __restrict__ b0, const float* __restrict__ b1, const float* __restrict__ b2,
    void* __restrict__ O0, void* __restrict__ O1, void* __restrict__ O2) {
  __shared__ bf16 As[2][128 * 64];   // 2 x 16 KB
  __shared__ bf16 Bs[2][128 * 64];   // 2 x 16 KB

  // ---- XCD-chunked swizzle ----
  const int NZ = (VARIANT == 0) ? 3 : 1;
  const int chunk = 49 * NZ;
  const int f = blockIdx.x + (blockIdx.y << 3) + blockIdx.z * 392;
  const int L = (f & 7) * chunk + (f >> 3);
  const int lx = L & 7;                            // N-tile
  const int lyz = L >> 3;
  const int ly = (VARIANT == 0) ? (lyz % 49) : lyz;  // M-tile
  const int z = (VARIANT == 0) ? (lyz / 49) : 0;     // qkv select

  const bf16* A = (z == 0) ? A0 : (z == 1) ? A1 : A2;
  const bf16* W = (z == 0) ? W0 : (z == 1) ? W1 : W2;
  const float* bias = (z == 0) ? b0 : (z == 1) ? b1 : b2;

  const int tid = threadIdx.x;
  const int lane = tid & 63;
  const int wid = tid >> 6;
  const int l16 = lane & 15;
  const int quad = lane >> 4;
  const int wm = wid >> 1;
  const int wn = wid & 1;

  const bf16* gA = A + (size_t)ly * 128 * D_;
  const bf16* gB = W + (size_t)lx * 128 * D_;

  const int srow = tid >> 3;
  const int lslot = (tid & 7) ^ (srow & 7);
  size_t sOff[4];
#pragma unroll
  for (int u = 0; u < 4; u++) sOff[u] = (size_t)(u * 32 + srow) * D_ + lslot * 8;

  int arow[4], brow[4], kslot[2];
#pragma unroll
  for (int i = 0; i < 4; i++) arow[i] = (wm * 64 + i * 16 + l16) * 64;
#pragma unroll
  for (int j = 0; j < 4; j++) brow[j] = (wn * 64 + j * 16 + l16) * 64;
#pragma unroll
  for (int kk = 0; kk < 2; kk++) kslot[kk] = ((kk * 4 + quad) ^ (l16 & 7)) * 8;

  floatx4 acc[4][4];
#pragma unroll
  for (int i = 0; i < 4; i++)
#pragma unroll
    for (int j = 0; j < 4; j++)
#pragma unroll
      for (int r = 0; r < 4; r++) acc[i][j][r] = 0.0f;

#pragma unroll
  for (int u = 0; u < 4; u++) {
    async_copy16(gA + sOff[u], &As[0][u * 2048 + tid * 8]);
    async_copy16(gB + sOff[u], &Bs[0][u * 2048 + tid * 8]);
  }
  WAITV0();
  BARRIER();

  for (int kt = 0; kt < KT_; ++kt) {
    const int cur = kt & 1;
    const bf16* Ab = As[cur];
    const bf16* Bb = Bs[cur];
    const bool pf = (kt + 1 < KT_);
    const bf16* pa = gA + (kt + 1) * 64;
    const bf16* pb = gB + (kt + 1) * 64;
    bf16* dA = As[cur ^ 1];
    bf16* dB = Bs[cur ^ 1];
    bf16x8 af[4], bfv[4];

#pragma unroll
    for (int i = 0; i < 4; i++) af[i] = *(const bf16x8*)(Ab + arow[i] + kslot[0]);
#pragma unroll
    for (int j = 0; j < 4; j++) bfv[j] = *(const bf16x8*)(Bb + brow[j] + kslot[0]);
    if (pf) {
#pragma unroll
      for (int u = 0; u < 4; u++) async_copy16(pa + sOff[u], dA + u * 2048 + tid * 8);
    }
    __builtin_amdgcn_s_setprio(1);
#pragma unroll
    for (int i = 0; i < 4; i++)
#pragma unroll
      for (int j = 0; j < 4; j++)
        acc[i][j] = __builtin_amdgcn_mfma_f32_16x16x32_bf16(af[i], bfv[j], acc[i][j], 0, 0, 0);
    __builtin_amdgcn_s_setprio(0);

#pragma unroll
    for (int i = 0; i < 4; i++) af[i] = *(const bf16x8*)(Ab + arow[i] + kslot[1]);
#pragma unroll
    for (int j = 0; j < 4; j++) bfv[j] = *(const bf16x8*)(Bb + brow[j] + kslot[1]);
    if (pf) {
#pragma unroll
      for (int u = 0; u < 4; u++) async_copy16(pb + sOff[u], dB + u * 2048 + tid * 8);
    }
    __builtin_amdgcn_s_setprio(1);
#pragma unroll
    for (int i = 0; i < 4; i++)
#pragma unroll
      for (int j = 0; j < 4; j++)
        acc[i][j] = __builtin_amdgcn_mfma_f32_16x16x32_bf16(af[i], bfv[j], acc[i][j], 0, 0, 0);
    __builtin_amdgcn_s_setprio(0);

    if (pf) {
      WAITV0();
      BARRIER();
    }
  }

  const int m0 = ly * 128 + wm * 64;
  const int n0 = lx * 128 + wn * 64;
#pragma unroll
  for (int j = 0; j < 4; j++) {
    const int col = n0 + j * 16 + l16;
    const float bv = bias[col];
#pragma unroll
    for (int i = 0; i < 4; i++) {
#pragma unroll
      for (int r = 0; r < 4; r++) {
        const int row = m0 + i * 16 + quad * 4 + r;
        float v = acc[i][j][r] + bv;
        if (VARIANT == 1) {
          ((float*)O0)[(size_t)row * D_ + col] = v;
        } else if (z < 2) {
          bf16* Cout = z ? (bf16*)O1 : (bf16*)O0;
          Cout[(size_t)row * D_ + col] = (bf16)v;
        } else {
          int b = row / N_;
          int n = row - b * N_;
          int h = col >> 7;
          int d = col & (DK_ - 1);
          ((bf16*)O2)[((size_t)((b * H_ + h) * DK_ + d)) * NPAD_ + n] = (bf16)v;
        }
      }
    }
  }
}

// ---------------------------------------------------------------------------
// Fused attention, ONE BLOCK PER (b,h): grid = 256 (1 block/CU).  Stage ALL
// of K (7x 32x128 subtiles, 56 KB) and V (7x 128x32 slabs, 56 KB) into LDS
// once -> single vmcnt(0)+barrier, then 4 row-tiles computed entirely from
// LDS with ZERO further barriers (P is wave-private).  K/V global traffic /4
// vs the per-tile version; 14 drains -> 1.
// LDS total = 56+56+29 = 141 KB (gfx950 allows up to 160 KB/workgroup).
// ---------------------------------------------------------------------------
__global__ __launch_bounds__(256) void attn_kernel(const bf16* __restrict__ Q,
                                                   const bf16* __restrict__ Kmat,
                                                   const bf16* __restrict__ Vt,
                                                   const half_t* __restrict__ Sb,
                                                   bf16* __restrict__ AO) {
  __shared__ bf16 Ks[7 * 4096];            // 56 KB: subtile jt = rows [jt*32, jt*32+32) x 128
  __shared__ bf16 Vs[7 * 4096];            // 56 KB: slab t7 = 128 d-rows x cols [t7*32, t7*32+32)
  __shared__ bf16 Pl[4 * 16 * PSTRIDE_];   // 29 KB: wave-private P

  const int bh = blockIdx.x;
  const int b = bh >> 3;
  const int h = bh & 7;
  const int tid = threadIdx.x;
  const int wave = tid >> 6;
  const int lane = tid & 63;
  const int l16 = lane & 15;
  const int quad = lane >> 4;

  // K staging: per subtile 512 units of 16B; 2 units/thread.  row=slot>>4,
  // phys col-slot holds logical (slot&15)^(row&7) -> pre-swizzled source.
  size_t kSrc[2];
  int kDst[2];
#pragma unroll
  for (int u = 0; u < 2; u++) {
    const int slot = u * 256 + tid;
    const int srow = slot >> 4;
    const int scs = slot & 15;
    kSrc[u] = (size_t)(b * N_ + srow) * D_ + h * DK_ + (scs ^ (srow & 7)) * 8;
    kDst[u] = slot * 8;
  }
  // V staging: per slab 512 units; row=slot>>2 (d index), phys col-slot
  // holds logical (slot&3)^(row&3).
  size_t vSrc[2];
#pragma unroll
  for (int u = 0; u < 2; u++) {
    const int slot = u * 256 + tid;
    const int vrow = slot >> 2;
    const int vcs = slot & 3;
    vSrc[u] = (size_t)bh * DK_ * NPAD_ + (size_t)vrow * NPAD_ + (vcs ^ (vrow & 3)) * 8;
  }

  // ---- stage EVERYTHING: 28 global_load_lds, one drain, one barrier ----
#pragma unroll
  for (int jt = 0; jt < 7; ++jt) {
    const size_t koff = (size_t)(jt * 32) * D_;
#pragma unroll
    for (int u = 0; u < 2; u++) async_copy16(Kmat + kSrc[u] + koff, Ks + jt * 4096 + kDst[u]);
  }
#pragma unroll
  for (int t7 = 0; t7 < 7; ++t7) {
#pragma unroll
    for (int u = 0; u < 2; u++) async_copy16(Vt + vSrc[u] + t7 * 32, Vs + t7 * 4096 + kDst[u]);
  }
  WAITV0();
  BARRIER();

  const float scale = 0.08838834764831845f;  // 1/sqrt(128)
  const half_t* bbase = Sb + ((size_t)bh * N_) * NPAD_;
  bf16* pw = Pl + wave * 16 * PSTRIDE_;
  const bf16* pr = pw + l16 * PSTRIDE_ + quad * 8;

  // ---- 4 row-tiles, all from LDS, no barriers (P is wave-private) ----
  for (int rt = 0; rt < 4; ++rt) {
    const int nrb = rt * 64 + wave * 16;

    // Q fragments for this row-tile
    const int na = nrb + l16;
    const bool nav = na < N_;
    const bf16* aptr = Q + ((size_t)(b * N_ + (nav ? na : 0))) * D_ + h * DK_ + quad * 8;
    bf16x8 afr[4];
#pragma unroll
    for (int kk = 0; kk < 4; kk++) {
      bf16x8 v = *(const bf16x8*)(aptr + kk * 32);
      if (!nav) {
#pragma unroll
        for (int e = 0; e < 8; e++) v[e] = (bf16)0.0f;
      }
      afr[kk] = v;
    }

    // QK^T
    floatx4 S[14];
#pragma unroll
    for (int j = 0; j < 14; j++)
#pragma unroll
      for (int r = 0; r < 4; r++) S[j][r] = 0.0f;

#pragma unroll
    for (int jt = 0; jt < 7; ++jt) {
      const bf16* Kb = Ks + jt * 4096;
      __builtin_amdgcn_s_setprio(1);
#pragma unroll
      for (int jj = 0; jj < 2; jj++) {
        const int mloc = jj * 16 + l16;
#pragma unroll
        for (int kk = 0; kk < 4; kk++) {
          bf16x8 bb = *(const bf16x8*)(Kb + mloc * 128 + ((kk * 4 + quad) ^ (l16 & 7)) * 8);
          S[jt * 2 + jj] = __builtin_amdgcn_mfma_f32_16x16x32_bf16(afr[kk], bb, S[jt * 2 + jj], 0, 0, 0);
        }
      }
      __builtin_amdgcn_s_setprio(0);
    }

    // scale + mask + max + weighted exp + P->LDS
    float inv[4];
#pragma unroll
    for (int r = 0; r < 4; r++) {
      const int n = nrb + quad * 4 + r;
      const bool nv = n < N_;
      const size_t brow = (size_t)(nv ? n : 0) * NPAD_;
      float mx = -1e30f;
#pragma unroll
      for (int j = 0; j < 14; j++) {
        const int m = j * 16 + l16;
        float s = (nv && m < N_) ? S[j][r] * scale : -1e30f;
        S[j][r] = s;
        mx = fmaxf(mx, s);
      }
#pragma unroll
      for (int off = 1; off < 16; off <<= 1) mx = fmaxf(mx, __shfl_xor(mx, off, 64));
      float sum = 0.0f;
#pragma unroll
      for (int j = 0; j < 14; j++) {
        const int m = j * 16 + l16;
        float w = (m < N_) ? (float)bbase[brow + m] : 0.0f;
        float e = w * __expf(S[j][r] - mx);
        sum += e;
        pw[(quad * 4 + r) * PSTRIDE_ + m] = (bf16)e;   // pad cols: e == 0 exactly
      }
#pragma unroll
      for (int off = 1; off < 16; off <<= 1) sum += __shfl_xor(sum, off, 64);
      inv[r] = 1.0f / sum;
    }
    // in-wave LDS write->read ordering handled by compiler lgkmcnt

    // PV
    floatx4 O[8];
#pragma unroll
    for (int j2 = 0; j2 < 8; j2++)
#pragma unroll
      for (int r = 0; r < 4; r++) O[j2][r] = 0.0f;

#pragma unroll
    for (int t7 = 0; t7 < 7; ++t7) {
      const bf16* Vb = Vs + t7 * 4096;
      bf16x8 a = *(const bf16x8*)(pr + t7 * 32);
      __builtin_amdgcn_s_setprio(1);
#pragma unroll
      for (int j2 = 0; j2 < 8; j2++) {
        bf16x8 bb = *(const bf16x8*)(Vb + (j2 * 16 + l16) * 32 + (quad ^ (l16 & 3)) * 8);
        O[j2] = __builtin_amdgcn_mfma_f32_16x16x32_bf16(a, bb, O[j2], 0, 0, 0);
      }
      __builtin_amdgcn_s_setprio(0);
    }

    // epilogue: scale by 1/l, store
#pragma unroll
    for (int r = 0; r < 4; r++) {
      const int n = nrb + quad * 4 + r;
      if (n < N_) {
#pragma unroll
        for (int j2 = 0; j2 < 8; j2++) {
          AO[((size_t)(b * N_ + n)) * D_ + h * DK_ + j2 * 16 + l16] = (bf16)(O[j2][r] * inv[r]);
        }
      }
    }
  }
}

// ---------------------------------------------------------------------------
extern "C" void kernel_launch(void* const* d_in, const int* in_sizes, int n_in,
                              void* d_out, int out_size, void* d_ws, size_t ws_size,
                              hipStream_t stream) {
  const float* xq = (const float*)d_in[0];
  const float* xk = (const float*)d_in[1];
  const float* xv = (const float*)d_in[2];
  const float* box = (const float*)d_in[3];
  const float* Wq = (const float*)d_in[4];
  const float* bq = (const float*)d_in[5];
  const float* Wk = (const float*)d_in[6];
  const float* bk = (const float*)d_in[7];
  const float* Wv = (const float*)d_in[8];
  const float* bv = (const float*)d_in[9];
  const float* Wo = (const float*)d_in[10];
  const float* bo = (const float*)d_in[11];
  const float* WGw = (const float*)d_in[12];
  const float* WGb = (const float*)d_in[13];

  size_t off = 0;
  char* wsc = (char*)d_ws;
  auto alloc = [&](size_t bytes) -> void* {
    void* p = wsc + off;
    off += (bytes + 255) & ~(size_t)255;
    return p;
  };
  bf16* xq_b = (bf16*)alloc((size_t)BN_ * D_ * 2);
  bf16* xk_b = (bf16*)alloc((size_t)BN_ * D_ * 2);
  bf16* xv_b = (bf16*)alloc((size_t)BN_ * D_ * 2);
  bf16* wq_b = (bf16*)alloc((size_t)D_ * D_ * 2);
  bf16* wk_b = (bf16*)alloc((size_t)D_ * D_ * 2);
  bf16* wv_b = (bf16*)alloc((size_t)D_ * D_ * 2);
  bf16* wo_b = (bf16*)alloc((size_t)D_ * D_ * 2);
  bf16* q_b = (bf16*)alloc((size_t)BN_ * D_ * 2);
  bf16* k_b = (bf16*)alloc((size_t)BN_ * D_ * 2);
  bf16* vt_b = (bf16*)alloc((size_t)BH_ * DK_ * NPAD_ * 2);
  bf16* ao_b = (bf16*)alloc((size_t)BN_ * D_ * 2);
  half_t* S = (half_t*)alloc((size_t)BH_ * N_ * NPAD_ * 2);

  const int n4x = BN_ * D_ / 4;
  const int n4w = D_ * D_ / 4;
  dim3 g3(n4x / 256, 3, 1);
  cvt3_kernel<<<g3, 256, 0, stream>>>(xq, xk, xv, xq_b, xk_b, xv_b, n4x);
  dim3 g4(n4w / 256, 4, 1);
  cvt4_kernel<<<g4, 256, 0, stream>>>(Wq, Wk, Wv, Wo, wq_b, wk_b, wv_b, wo_b, n4w);

  geo_kernel<<<(B_ * N_ * N_) / 256, 256, 0, stream>>>(box, WGw, WGb, S);

  // zero Vt so its pad columns (n in [196,224)) are 0, not poison
  hipMemsetAsync(vt_b, 0, (size_t)BH_ * DK_ * NPAD_ * 2, stream);

  dim3 gqkv(D_ / 128, BN_ / 128, 3);
  gemm2p<0><<<gqkv, 256, 0, stream>>>(xq_b, xk_b, xv_b, wq_b, wk_b, wv_b, bq, bk, bv,
                                      q_b, k_b, vt_b);

  attn_kernel<<<BH_, 256, 0, stream>>>(q_b, k_b, vt_b, S, ao_b);

  dim3 gout(D_ / 128, BN_ / 128, 1);
  gemm2p<1><<<gout, 256, 0, stream>>>(ao_b, nullptr, nullptr, wo_b, nullptr, nullptr,
                                      bo, nullptr, nullptr, d_out, nullptr, nullptr);
}